// Round 6
// baseline (183.777 us; speedup 1.0000x reference)
//
#include <hip/hip_runtime.h>
#include <math.h>

typedef __attribute__((ext_vector_type(2))) float f32x2;
typedef __attribute__((ext_vector_type(4))) float f32x4;

// Problem dims (fixed): (B=4, 1, D=160, H=192, W=192) f32
#define BDIM 4
#define DDIM 160
#define HDIM 192
#define WDIM 192
#define NTOT (BDIM * DDIM * HDIM * WDIM)

#define TH 8
#define TW 64
#define SEG 20               // output D-slices per block
#define NSEG (DDIM / SEG)    // 8
#define NS  (SEG + 6)        // 26 input slices
#define NTH 512

#define RHH (TH + 6)         // 14
#define RWW (TW + 6)         // 70
#define NRAW (RHH * RWW)     // 980

#define HBSTR 72             // hb row stride (elements), 16B-aligned rows

template<int N> struct IC { static constexpr int v = N; };

__device__ __forceinline__ float rcp_fast(float x) {
#if __has_builtin(__builtin_amdgcn_rcpf)
    return __builtin_amdgcn_rcpf(x);
#else
    return 1.0f / x;
#endif
}

__global__ __launch_bounds__(NTH, 4)
void nq_main(const float* __restrict__ X,   // recon
             const float* __restrict__ Y,   // target
             float* __restrict__ acc)       // [0]=ssim_sum [1]=l1_num [2]=l1_den
{
    constexpr float Gc[7] = {
        0.03663285f, 0.11128076f, 0.21674532f, 0.27068215f,
        0.21674532f, 0.11128076f, 0.03663285f };
    constexpr float C1f = 4.0e-4f;   // (0.01*2)^2
    constexpr float C2f = 3.6e-3f;   // (0.03*2)^2

    // ALL single-buffered (hazards barrier-separated by phase order):
    // ~29.7 KB -> 3 blocks/CU (SGPR-capped at 24 waves).
    __shared__ __align__(16) f32x2 raw[NRAW];           //  7,840 B (x,y)
    __shared__ __align__(16) f32x2 hbA[TH][HBSTR];      //  4,608 B (hx,hy)
    __shared__ __align__(16) f32x2 hbB[TH][HBSTR];      //  4,608 B (hxx,hyy)
    __shared__ __align__(16) float hbC[TH][HBSTR];      //  2,304 B (hxy)
    __shared__ __align__(16) f32x2 wbA[TH][TW];         //  4,096 B
    __shared__ __align__(16) f32x2 wbB[TH][TW];         //  4,096 B
    __shared__ __align__(16) float wbC[TH][TW];         //  2,048 B
    __shared__ float red[NTH / 64][3];

    const int wt  = blockIdx.x;            // 0..2
    const int ht  = blockIdx.y;            // 0..23
    const int b   = blockIdx.z >> 3;       // 0..3
    const int seg = blockIdx.z & 7;        // 0..7
    const int h0 = ht * TH, w0 = wt * TW;
    const int dbase = seg * SEG;
    const long long bbase = (long long)b * (DDIM * HDIM * WDIM);
    const int t = threadIdx.x;

    // ---- commit/load invariants: 2 raw points/thread (980 = 512 + 468) ----
    int goff[2]; bool ok[2], inter[2];
    #pragma unroll
    for (int i = 0; i < 2; ++i) {
        const int idx = t + i * NTH;
        const int hh = idx / RWW, ww = idx - hh * RWW;
        const int h = h0 + hh - 3, w = w0 + ww - 3;
        bool o_ = ((unsigned)h < HDIM) && ((unsigned)w < WDIM);
        bool in_ = ((unsigned)(hh - 3) < TH) && ((unsigned)(ww - 3) < TW);
        if (i == 1 && idx >= NRAW) { o_ = false; in_ = false; }
        ok[i] = o_; inter[i] = in_;
        goff[i] = h * WDIM + w;
    }
    const bool has1 = (t + NTH) < NRAW;    // t < 468

    // ---- P2 invariants: H-blur items (560 = 512 + 48) ----
    const int p2r0 = t / RWW, p2w0 = t - p2r0 * RWW;
    const int p2r1 = (t + NTH) / RWW, p2w1 = (t + NTH) - p2r1 * RWW;
    const bool p2has1 = (t + NTH) < TH * RWW;

    // ---- P3 invariants: W-blur, 4 outputs/thread, 384 items ----
    const int p3p = t >> 7;                // plane 0=A 1=B 2=C
    const int p3r = (t >> 4) & 7;          // row
    const int p3q = t & 15;                // quad of output cols
    const bool p3act = t < 384;

    // ---- P4 invariants: 1 pixel/thread ----
    const int pw = t & 63, ph = t >> 6;

    float ssum = 0.f, l1n = 0.f, l1d = 0.f;
    f32x2 wA[7], wB[7]; float wC[7];       // D-window, statically rotated
    float pfx[2], pfy[2];

    auto loadslice = [&](int s) {          // prefetch raw slice s into regs
        const int d_g = dbase - 3 + s;
        const bool dok = (unsigned)d_g < (unsigned)DDIM;
        const long long sb = bbase + (long long)d_g * (HDIM * WDIM);
        #pragma unroll
        for (int i = 0; i < 2; ++i) {
            const bool l = dok && ok[i];
            pfx[i] = l ? X[sb + goff[i]] : 0.f;
            pfy[i] = l ? Y[sb + goff[i]] : 0.f;
        }
    };

    auto commit = [&](int s) {             // write prefetched slice s to LDS
        raw[t] = (f32x2){pfx[0], pfy[0]};
        if (has1) raw[t + NTH] = (f32x2){pfx[1], pfy[1]};
        if (s >= 3 && s <= SEG + 2) {
            #pragma unroll
            for (int i = 0; i < 2; ++i) if (inter[i]) {
                const float wgt = (pfy[i] > -0.9f) ? 5.f : 1.f;
                l1n += wgt * fabsf(pfx[i] - pfy[i]);
                l1d += wgt;
            }
        }
    };

    auto p2item = [&](int r, int w) {
        f32x2 aA = {0.f, 0.f}, aB = {0.f, 0.f}; float aC = 0.f;
        #pragma unroll
        for (int k = 0; k < 7; ++k) {
            const f32x2 p = raw[(r + k) * RWW + w];
            const float g = Gc[k];
            aA += g * p;
            aB += (g * p) * p;
            aC += g * (p.x * p.y);
        }
        hbA[r][w] = aA; hbB[r][w] = aB; hbC[r][w] = aC;
    };

    auto p3pk = [&](const f32x2 (*src)[HBSTR], f32x2 (*dst)[TW], int r, int q) {
        const f32x2* row = &src[r][0];
        f32x2 v[10];
        #pragma unroll
        for (int j = 0; j < 5; ++j) {
            const f32x4 x4 = *(const f32x4*)(row + 4 * q + 2 * j);
            v[2 * j]     = (f32x2){x4.x, x4.y};
            v[2 * j + 1] = (f32x2){x4.z, x4.w};
        }
        #pragma unroll
        for (int o = 0; o < 4; o += 2) {
            f32x2 a0 = {0.f, 0.f}, a1 = {0.f, 0.f};
            #pragma unroll
            for (int k = 0; k < 7; ++k) {
                a0 += Gc[k] * v[o + k];
                a1 += Gc[k] * v[o + 1 + k];
            }
            *(f32x4*)(&dst[r][4 * q + o]) = (f32x4){a0.x, a0.y, a1.x, a1.y};
        }
    };

    auto p3sc = [&](int r, int q) {
        const float* row = &hbC[r][0];
        float v[10];
        #pragma unroll
        for (int j = 0; j < 2; ++j) {
            const f32x4 x4 = *(const f32x4*)(row + 4 * q + 4 * j);
            v[4 * j] = x4.x; v[4 * j + 1] = x4.y; v[4 * j + 2] = x4.z; v[4 * j + 3] = x4.w;
        }
        const f32x2 x2 = *(const f32x2*)(row + 4 * q + 8);
        v[8] = x2.x; v[9] = x2.y;
        float o[4];
        #pragma unroll
        for (int j = 0; j < 4; ++j) {
            float a = 0.f;
            #pragma unroll
            for (int k = 0; k < 7; ++k) a += Gc[k] * v[j + k];
            o[j] = a;
        }
        *(f32x4*)(&wbC[r][4 * q]) = (f32x4){o[0], o[1], o[2], o[3]};
    };

    // Step ps, phase 1: P2 H-blurs slice ps (raw->hb), P4 pushes wb(ps-1) into
    //   the D-window (slot (ps-1)%7, static).
    // barrier
    // Phase 2: commit(ps+1) (raw is free), issue loads for ps+2, P3 W-blurs
    //   slice ps (hb->wb), SSIM-emit output od=ps-7 from the window.
    // barrier
    auto phase = [&](auto PPc, int it) {
        constexpr int PP = PPc.v;
        constexpr int SLOT = (PP + 6) % 7;           // (ps-1)%7
        const int ps = it * 7 + PP;

        // ---- phase 1 ----
        if (ps <= NS - 1) {                          // P2: raw(ps) -> hb(ps)
            p2item(p2r0, p2w0);
            if (p2has1) p2item(p2r1, p2w1);
        }
        if (ps >= 1 && ps <= NS) {                   // P4 push: wb(ps-1)
            wA[SLOT] = wbA[ph][pw];
            wB[SLOT] = wbB[ph][pw];
            wC[SLOT] = wbC[ph][pw];
        }
        __syncthreads();

        // ---- phase 2 ----
        if (ps <= NS - 2) commit(ps + 1);            // raw consumed by P2 above
        if (ps <= NS - 3) loadslice(ps + 2);         // lands during next step
        if (ps <= NS - 1) {                          // P3: hb(ps) -> wb(ps)
            if (p3act) {
                if (p3p == 0)      p3pk(hbA, wbA, p3r, p3q);
                else if (p3p == 1) p3pk(hbB, wbB, p3r, p3q);
                else               p3sc(p3r, p3q);
            }
        }
        if (ps >= 7 && ps <= NS) {                   // emit od = ps-7
            f32x2 mu = {0.f, 0.f}, e2 = {0.f, 0.f}; float exy = 0.f;
            #pragma unroll
            for (int k = 0; k < 7; ++k) {
                const int s = (PP + k) % 7;          // slice ps-7+k
                const float g = Gc[k];
                mu += g * wA[s]; e2 += g * wB[s]; exy += g * wC[s];
            }
            const float mux2 = mu.x * mu.x, muy2 = mu.y * mu.y, muxy = mu.x * mu.y;
            const float sx2 = e2.x - mux2, sy2 = e2.y - muy2, sxy = exy - muxy;
            const float num = (2.f * muxy + C1f) * (2.f * sxy + C2f);
            const float den = (mux2 + muy2 + C1f) * (sx2 + sy2 + C2f);
            ssum += num * rcp_fast(den);
        }
        __syncthreads();
    };

    // prologue: slice 0 committed, slice 1 prefetched into regs
    loadslice(0);
    commit(0);
    loadslice(1);
    __syncthreads();

    for (int it = 0; it < 4; ++it) {       // ps = 0..27 (27 = all-guards-false pad)
        phase(IC<0>{}, it); phase(IC<1>{}, it); phase(IC<2>{}, it);
        phase(IC<3>{}, it); phase(IC<4>{}, it); phase(IC<5>{}, it);
        phase(IC<6>{}, it);
    }

    // ---- block reduce + atomics ----
    #pragma unroll
    for (int off = 32; off > 0; off >>= 1) {
        ssum += __shfl_down(ssum, off, 64);
        l1n  += __shfl_down(l1n,  off, 64);
        l1d  += __shfl_down(l1d,  off, 64);
    }
    const int wave = t >> 6, lane = t & 63;
    if (lane == 0) { red[wave][0] = ssum; red[wave][1] = l1n; red[wave][2] = l1d; }
    __syncthreads();
    if (t == 0) {
        float s = 0.f, n = 0.f, dn = 0.f;
        #pragma unroll
        for (int i = 0; i < NTH / 64; ++i) {
            s += red[i][0]; n += red[i][1]; dn += red[i][2];
        }
        atomicAdd(&acc[0], s);
        atomicAdd(&acc[1], n);
        atomicAdd(&acc[2], dn);
    }
}

__global__ void nq_final(const float* __restrict__ acc,
                         const float* __restrict__ vq,
                         float* __restrict__ out)
{
    const float ssim_mean = acc[0] / (float)NTOT;
    out[0] = acc[1] / acc[2] + 0.5f * (1.0f - ssim_mean) + vq[0];
}

extern "C" void kernel_launch(void* const* d_in, const int* in_sizes, int n_in,
                              void* d_out, int out_size, void* d_ws, size_t ws_size,
                              hipStream_t stream)
{
    const float* X  = (const float*)d_in[0];  // recon
    const float* Y  = (const float*)d_in[1];  // target
    const float* vq = (const float*)d_in[2];  // scalar
    float* out = (float*)d_out;
    float* acc = (float*)d_ws;

    hipMemsetAsync(acc, 0, 3 * sizeof(float), stream);

    dim3 grid(WDIM / TW, HDIM / TH, BDIM * NSEG);   // 3 x 24 x 32 = 2304 blocks
    nq_main<<<grid, NTH, 0, stream>>>(X, Y, acc);
    nq_final<<<1, 1, 0, stream>>>(acc, vq, out);
}

// Round 7
// 177.701 us; speedup vs baseline: 1.0342x; 1.0342x over previous
//
#include <hip/hip_runtime.h>
#include <math.h>

typedef __attribute__((ext_vector_type(2))) float f32x2;
typedef __attribute__((ext_vector_type(4))) float f32x4;

// Problem dims (fixed): (B=4, 1, D=160, H=192, W=192) f32
#define BDIM 4
#define DDIM 160
#define HDIM 192
#define WDIM 192
#define NTOT (BDIM * DDIM * HDIM * WDIM)

#define TH 8
#define TW 64
#define SEG 32               // output D-slices per block
#define NSEG (DDIM / SEG)    // 5
#define NS  (SEG + 6)        // 38 input slices
#define NTH 512

#define RHH (TH + 6)         // 14
#define RWW (TW + 6)         // 70
#define NRAW (RHH * RWW)     // 980

#define HBSTR 72             // hb row stride (f32x2 elements), 16B-aligned rows

template<int N> struct IC { static constexpr int v = N; };

__device__ __forceinline__ float rcp_fast(float x) {
#if __has_builtin(__builtin_amdgcn_rcpf)
    return __builtin_amdgcn_rcpf(x);
#else
    return 1.0f / x;
#endif
}

__global__ __launch_bounds__(NTH, 4)
void nq_main(const float* __restrict__ X,   // recon
             const float* __restrict__ Y,   // target
             float* __restrict__ acc)       // [0]=ssim_sum [1]=l1_num [2]=l1_den
{
    constexpr float Gc[7] = {
        0.03663285f, 0.11128076f, 0.21674532f, 0.27068215f,
        0.21674532f, 0.11128076f, 0.03663285f };
    constexpr float C1f = 4.0e-4f;   // (0.01*2)^2
    constexpr float C2f = 3.6e-3f;   // (0.03*2)^2

    // s/d basis: fields (s,d) and (s^2,d^2) -> 4 blur planes in 2 packed f32x2.
    // Double-buffered single-barrier systolic pipeline (R5 structure).
    // LDS = 50.6 KB -> 3 blocks/CU.
    __shared__ __align__(16) f32x2 raw[2][NRAW];        // 15,680 B (s,d)
    __shared__ __align__(16) f32x2 hbA[2][TH][HBSTR];   //  9,216 B H-blur (s,d)
    __shared__ __align__(16) f32x2 hbB[2][TH][HBSTR];   //  9,216 B H-blur (s2,d2)
    __shared__ __align__(16) f32x2 wbA[2][TH][TW];      //  8,192 B
    __shared__ __align__(16) f32x2 wbB[2][TH][TW];      //  8,192 B
    __shared__ float red[NTH / 64][3];

    const int wt  = blockIdx.x;            // 0..2
    const int ht  = blockIdx.y;            // 0..23
    const int b   = blockIdx.z / NSEG;     // 0..3
    const int seg = blockIdx.z - b * NSEG; // 0..4
    const int h0 = ht * TH, w0 = wt * TW;
    const int dbase = seg * SEG;
    const long long bbase = (long long)b * (DDIM * HDIM * WDIM);
    const int t = threadIdx.x;

    // ---- commit/load invariants: 2 raw points/thread (980 = 512 + 468) ----
    int goff[2]; bool ok[2], inter[2];
    #pragma unroll
    for (int i = 0; i < 2; ++i) {
        const int idx = t + i * NTH;
        const int hh = idx / RWW, ww = idx - hh * RWW;
        const int h = h0 + hh - 3, w = w0 + ww - 3;
        bool o_ = ((unsigned)h < HDIM) && ((unsigned)w < WDIM);
        bool in_ = ((unsigned)(hh - 3) < TH) && ((unsigned)(ww - 3) < TW);
        if (i == 1 && idx >= NRAW) { o_ = false; in_ = false; }
        ok[i] = o_; inter[i] = in_;
        goff[i] = h * WDIM + w;
    }
    const bool has1 = (t + NTH) < NRAW;    // t < 468

    // ---- P2 invariants: H-blur items (560 = 512 + 48 extra on wave 7) ----
    const int p2r0 = t / RWW, p2w0 = t - p2r0 * RWW;
    const bool p2has1 = (t >= 448) && (t < 496);       // items 512..559
    const int p2r1 = (t + 64) / RWW, p2w1 = (t + 64) - p2r1 * RWW;

    // ---- P3 invariants: W-blur, 4 outputs/thread, 256 items (waves 0..3) ----
    const int p3p = t >> 7;                // plane 0=A 1=B
    const int p3r = (t >> 4) & 7;          // row
    const int p3q = t & 15;                // quad of output cols
    const bool p3act = t < 256;

    // ---- P4 invariants: 1 pixel/thread ----
    const int pw = t & 63, ph = t >> 6;

    float ssum = 0.f, l1n = 0.f, l1d = 0.f;
    f32x2 wA[7], wB[7];                    // D-window (28 VGPRs), static slots
    float pfs[2], pfd[2];                  // prefetched (s,d)

    auto loadslice = [&](int s) {          // prefetch raw slice s; fused L1
        const int d_g = dbase - 3 + s;
        const bool dok = (unsigned)d_g < (unsigned)DDIM;
        const long long sb = bbase + (long long)d_g * (HDIM * WDIM);
        const bool l1on = (s >= 3) && (s <= SEG + 2);
        #pragma unroll
        for (int i = 0; i < 2; ++i) {
            const bool l = dok && ok[i];
            const float xv = l ? X[sb + goff[i]] : 0.f;
            const float yv = l ? Y[sb + goff[i]] : 0.f;
            if (l1on && inter[i]) {        // exact x,y here
                const float wgt = (yv > -0.9f) ? 5.f : 1.f;
                l1n += wgt * fabsf(xv - yv);
                l1d += wgt;
            }
            pfs[i] = xv + yv;
            pfd[i] = xv - yv;
        }
    };

    auto commit = [&](int s) {             // write prefetched slice s to LDS
        const int rb = s & 1;
        raw[rb][t] = (f32x2){pfs[0], pfd[0]};
        if (has1) raw[rb][t + NTH] = (f32x2){pfs[1], pfd[1]};
    };

    auto p2item = [&](int rb, int r, int w) {
        f32x2 aA = {0.f, 0.f}, aB = {0.f, 0.f};
        #pragma unroll
        for (int k = 0; k < 7; ++k) {
            const f32x2 p = raw[rb][(r + k) * RWW + w];
            const float g = Gc[k];
            aA += g * p;                   // pk_fma
            const f32x2 p2v = p * p;       // pk_mul
            aB += g * p2v;                 // pk_fma
        }
        hbA[rb][r][w] = aA; hbB[rb][r][w] = aB;
    };

    auto p3pk = [&](const f32x2 (*src)[HBSTR], f32x2 (*dst)[TW], int r, int q) {
        const f32x2* row = &src[r][0];
        f32x2 v[10];
        #pragma unroll
        for (int j = 0; j < 5; ++j) {
            const f32x4 x4 = *(const f32x4*)(row + 4 * q + 2 * j);
            v[2 * j]     = (f32x2){x4.x, x4.y};
            v[2 * j + 1] = (f32x2){x4.z, x4.w};
        }
        #pragma unroll
        for (int o = 0; o < 4; o += 2) {
            f32x2 a0 = {0.f, 0.f}, a1 = {0.f, 0.f};
            #pragma unroll
            for (int k = 0; k < 7; ++k) {
                a0 += Gc[k] * v[o + k];
                a1 += Gc[k] * v[o + 1 + k];
            }
            *(f32x4*)(&dst[r][4 * q + o]) = (f32x4){a0.x, a0.y, a1.x, a1.y};
        }
    };

    // step ps: commit(ps+1); prefetch ps+2; P2(ps): raw->hb; P3(ps-1): hb->wb;
    // P4 push wb(ps-2) into window slot ps%7; emit output od=ps-8 (ps>=8).
    // ONE barrier per step; all hazards separated by dbuf parity.
    auto phase = [&](auto PPc, int it) {
        constexpr int PP = PPc.v;
        const int ps = it * 7 + PP;
        const int par = ps & 1;

        if (ps <= NS - 2) commit(ps + 1);            // -> raw[(ps+1)&1]
        if (ps <= NS - 3) loadslice(ps + 2);         // regs, lands during compute

        if (ps <= NS - 1) {                          // P2: raw[ps&1] -> hb[ps&1]
            p2item(par, p2r0, p2w0);
            if (p2has1) p2item(par, p2r1, p2w1);
        }
        if (ps >= 1 && ps <= NS) {                   // P3: hb[(ps-1)&1] -> wb[(ps-1)&1]
            const int hp = par ^ 1;
            if (p3act) {
                if (p3p == 0) p3pk(hbA[hp], wbA[hp], p3r, p3q);
                else          p3pk(hbB[hp], wbB[hp], p3r, p3q);
            }
        }
        if (ps >= 2 && ps <= NS + 1) {               // P4: push wb(ps-2) = wb[par]
            wA[PP] = wbA[par][ph][pw];
            wB[PP] = wbB[par][ph][pw];
            if (ps >= 8) {                           // emit od = ps-8
                f32x2 mu = {0.f, 0.f}, e2 = {0.f, 0.f};
                #pragma unroll
                for (int k = 0; k < 7; ++k) {
                    const int s = (PP + 1 + k) % 7;
                    const float g = Gc[k];
                    mu += g * wA[s]; e2 += g * wB[s];
                }
                const float P = mu.x * mu.x, Q = mu.y * mu.y;
                const float u  = 0.5f * (P + Q);
                const float v_ = 0.5f * (P - Q);
                const float a2 = 0.5f * (e2.x + e2.y);
                const float b2 = 0.5f * (e2.x - e2.y);
                const float num = (v_ + C1f) * (b2 - v_ + C2f);
                const float den = (u  + C1f) * (a2 - u  + C2f);
                ssum += num * rcp_fast(den);
            }
        }
        __syncthreads();
    };

    // prologue: slice 0 committed, slice 1 prefetched into regs
    loadslice(0);
    commit(0);
    loadslice(1);
    __syncthreads();

    for (int it = 0; it < 6; ++it) {       // ps = 0..41 (40,41 are no-op pads)
        phase(IC<0>{}, it); phase(IC<1>{}, it); phase(IC<2>{}, it);
        phase(IC<3>{}, it); phase(IC<4>{}, it); phase(IC<5>{}, it);
        phase(IC<6>{}, it);
    }

    // ---- block reduce + atomics ----
    #pragma unroll
    for (int off = 32; off > 0; off >>= 1) {
        ssum += __shfl_down(ssum, off, 64);
        l1n  += __shfl_down(l1n,  off, 64);
        l1d  += __shfl_down(l1d,  off, 64);
    }
    const int wave = t >> 6, lane = t & 63;
    if (lane == 0) { red[wave][0] = ssum; red[wave][1] = l1n; red[wave][2] = l1d; }
    __syncthreads();
    if (t == 0) {
        float s = 0.f, n = 0.f, dn = 0.f;
        #pragma unroll
        for (int i = 0; i < NTH / 64; ++i) {
            s += red[i][0]; n += red[i][1]; dn += red[i][2];
        }
        atomicAdd(&acc[0], s);
        atomicAdd(&acc[1], n);
        atomicAdd(&acc[2], dn);
    }
}

__global__ void nq_final(const float* __restrict__ acc,
                         const float* __restrict__ vq,
                         float* __restrict__ out)
{
    const float ssim_mean = acc[0] / (float)NTOT;
    out[0] = acc[1] / acc[2] + 0.5f * (1.0f - ssim_mean) + vq[0];
}

extern "C" void kernel_launch(void* const* d_in, const int* in_sizes, int n_in,
                              void* d_out, int out_size, void* d_ws, size_t ws_size,
                              hipStream_t stream)
{
    const float* X  = (const float*)d_in[0];  // recon
    const float* Y  = (const float*)d_in[1];  // target
    const float* vq = (const float*)d_in[2];  // scalar
    float* out = (float*)d_out;
    float* acc = (float*)d_ws;

    hipMemsetAsync(acc, 0, 3 * sizeof(float), stream);

    dim3 grid(WDIM / TW, HDIM / TH, BDIM * NSEG);   // 3 x 24 x 20 = 1440 blocks
    nq_main<<<grid, NTH, 0, stream>>>(X, Y, acc);
    nq_final<<<1, 1, 0, stream>>>(acc, vq, out);
}